// Round 10
// baseline (166.732 us; speedup 1.0000x reference)
//
#include <hip/hip_runtime.h>
#include <hip/hip_bf16.h>
#include <stdint.h>

typedef __attribute__((ext_vector_type(8))) short short8;
typedef __attribute__((ext_vector_type(4))) float floatx4;

#define FEAT_DIM 1536
#define QD 64
#define NROWS 8192
#define TT 513

__device__ __forceinline__ unsigned short f2bf(float x) {
  union { float f; unsigned u; } t; t.f = x;
  unsigned r = t.u + 0x7fffu + ((t.u >> 16) & 1u);
  return (unsigned short)(r >> 16);
}
__device__ __forceinline__ float bf2f(unsigned short u) {
  union { float f; unsigned u; } t; t.u = ((unsigned)u) << 16;
  return t.f;
}
// monotone float->uint map (order-preserving), low 4 bits freed for an index
__device__ __forceinline__ unsigned packkey(float f, int idx) {
  unsigned x = __float_as_uint(f);
  unsigned m = (unsigned)((int)x >> 31);
  unsigned u = x ^ (m | 0x80000000u);
  return (u & ~15u) | (unsigned)idx;
}
__device__ __forceinline__ float unpackkey(unsigned u) {
  u &= ~15u;
  unsigned x = (u & 0x80000000u) ? (u ^ 0x80000000u) : ~u;
  return __uint_as_float(x);
}

// K1: sf = win @ proj (MFMA bf16), proj transposed+converted on the fly.
// Also zero-inits cnt[256]/cnt2/psum (ws is poisoned 0xAA before every launch).
__global__ __launch_bounds__(256, 4) void k_sf(const float* __restrict__ feat,
                                               const float* __restrict__ proj,
                                               unsigned short* __restrict__ sfb,
                                               float* __restrict__ sq,
                                               unsigned* __restrict__ cnt,
                                               float* __restrict__ psum,
                                               unsigned* __restrict__ cnt2) {
  if (threadIdx.x == 0) {
    if (blockIdx.x < 256) cnt[blockIdx.x] = 0u;
    else if (blockIdx.x == 256) { *psum = 0.0f; *cnt2 = 0u; }
  }
  const int tid = threadIdx.x;
  const int wave = tid >> 6, lane = tid & 63;
  const int q = lane >> 4, n = lane & 15;
  const int rbase = blockIdx.x * 16;
  const int row = rbase + n;
  const int b = row >> 9, ti = row & 511;
  const float* fb = feat + (size_t)(b * TT + ti) * FEAT_DIM;
  const int kw = wave * 384;

  floatx4 acc0 = {0,0,0,0}, acc1 = {0,0,0,0}, acc2 = {0,0,0,0}, acc3 = {0,0,0,0};

  int koff = kw + q * 8;
  floatx4 f0 = *(const floatx4*)(fb + koff);
  floatx4 f1 = *(const floatx4*)(fb + koff + 4);
  floatx4 g0 = *(const floatx4*)(fb + FEAT_DIM + koff);
  floatx4 g1 = *(const floatx4*)(fb + FEAT_DIM + koff + 4);

  for (int ks = 0; ks < 12; ++ks) {
    floatx4 nf0, nf1, ng0, ng1;
    if (ks < 11) {
      int ko = kw + (ks + 1) * 32 + q * 8;
      nf0 = *(const floatx4*)(fb + ko);
      nf1 = *(const floatx4*)(fb + ko + 4);
      ng0 = *(const floatx4*)(fb + FEAT_DIM + ko);
      ng1 = *(const floatx4*)(fb + FEAT_DIM + ko + 4);
    }
    const float* pp = proj + (size_t)(kw + ks * 32 + q * 8) * QD + n;
    union { unsigned short u[8]; short8 v; } B0, B1, B2, B3;
#pragma unroll
    for (int j = 0; j < 8; ++j) {
      B0.u[j] = f2bf(pp[j * QD]);
      B1.u[j] = f2bf(pp[j * QD + 16]);
      B2.u[j] = f2bf(pp[j * QD + 32]);
      B3.u[j] = f2bf(pp[j * QD + 48]);
    }
    __builtin_amdgcn_sched_barrier(0);
    union { unsigned short u[8]; short8 v; } A;
#pragma unroll
    for (int j = 0; j < 4; ++j) A.u[j] = f2bf(0.5f * (f0[j] + g0[j]));
#pragma unroll
    for (int j = 0; j < 4; ++j) A.u[4 + j] = f2bf(0.5f * (f1[j] + g1[j]));
    acc0 = __builtin_amdgcn_mfma_f32_16x16x32_bf16(A.v, B0.v, acc0, 0, 0, 0);
    acc1 = __builtin_amdgcn_mfma_f32_16x16x32_bf16(A.v, B1.v, acc1, 0, 0, 0);
    acc2 = __builtin_amdgcn_mfma_f32_16x16x32_bf16(A.v, B2.v, acc2, 0, 0, 0);
    acc3 = __builtin_amdgcn_mfma_f32_16x16x32_bf16(A.v, B3.v, acc3, 0, 0, 0);
    if (ks < 11) { f0 = nf0; f1 = nf1; g0 = ng0; g1 = ng1; }
  }

  __shared__ float part[4][16][64];
#pragma unroll
  for (int r = 0; r < 4; ++r) {
    part[wave][q * 4 + r][0 * 16 + n] = acc0[r];
    part[wave][q * 4 + r][1 * 16 + n] = acc1[r];
    part[wave][q * 4 + r][2 * 16 + n] = acc2[r];
    part[wave][q * 4 + r][3 * 16 + n] = acc3[r];
  }
  __syncthreads();
  {
    const int r = tid >> 4;
    const int c0 = (tid & 15) * 4;
    float sqp = 0.0f;
    union { unsigned short u[4]; uint2 d; } P;
#pragma unroll
    for (int j = 0; j < 4; ++j) {
      float v = part[0][r][c0 + j] + part[1][r][c0 + j] +
                part[2][r][c0 + j] + part[3][r][c0 + j];
      P.u[j] = f2bf(v);
      float bv = bf2f(P.u[j]);
      sqp += bv * bv;
    }
    *(uint2*)(sfb + (size_t)(rbase + r) * QD + c0) = P.d;
#pragma unroll
    for (int off = 1; off < 16; off <<= 1) sqp += __shfl_xor(sqp, off, 64);
    if ((tid & 15) == 0) sq[rbase + r] = sqp;
  }
}

// K2 (fused): pairwise-dot + top-16 + tournament + last-block merge + StreamNorm.
// Lists pinned to arch VGPRs via inline-asm "v" constraints; waves_per_eu(4,4)
// pins the register budget to 128 so the compiler doesn't split to AGPRs.
// Cross-block tail uses ONLY relaxed agent-scope atomics (no threadfence/inv —
// R8's 1024 buffer_inv's tripled dur; __syncthreads drains vmcnt pre-counter).
__global__ __launch_bounds__(256) __attribute__((amdgpu_waves_per_eu(4, 4)))
void k_knn(const unsigned short* __restrict__ sfb,
           const float* __restrict__ sq,
           float* __restrict__ tops,
           float* __restrict__ intrew,
           unsigned* __restrict__ cnt,
           unsigned* __restrict__ cnt2,
           float* __restrict__ psum,
           const float* __restrict__ reward,
           float* __restrict__ out) {
  const int tid = threadIdx.x;
  const int wave = tid >> 6, lane = tid & 63;
  const int q = lane >> 4, n = lane & 15;
  const int rg = blockIdx.x >> 2;
  const int ib = rg * 32;
  const int js = blockIdx.x & 3;
  const short8* sfv = (const short8*)sfb;

  short8 b0 = sfv[(ib + n) * 8 + q];
  short8 b1 = sfv[(ib + n) * 8 + 4 + q];
  short8 b2 = sfv[(ib + 16 + n) * 8 + q];
  short8 b3 = sfv[(ib + 16 + n) * 8 + 4 + q];

  float lst0[16], lst1[16];
#pragma unroll
  for (int k = 0; k < 16; ++k) { lst0[k] = 3.0e38f; lst1[k] = 3.0e38f; }

  const int j0 = js * 2048 + wave * 512;
  short8 A0 = sfv[(j0 + n) * 8 + q];
  short8 A1 = sfv[(j0 + n) * 8 + 4 + q];
  floatx4 s4 = *(const floatx4*)(sq + j0 + q * 4);

  for (int jt = 0; jt < 512; jt += 16) {
    const int jn = j0 + jt + 16;   // final prefetch overruns into ws scratch: harmless
    short8 nA0 = sfv[(jn + n) * 8 + q];
    short8 nA1 = sfv[(jn + n) * 8 + 4 + q];
    floatx4 ns4 = *(const floatx4*)(sq + jn + q * 4);
    __builtin_amdgcn_sched_barrier(0);

    floatx4 acc0 = {0, 0, 0, 0};
    acc0 = __builtin_amdgcn_mfma_f32_16x16x32_bf16(A0, b0, acc0, 0, 0, 0);
    acc0 = __builtin_amdgcn_mfma_f32_16x16x32_bf16(A1, b1, acc0, 0, 0, 0);
    floatx4 acc1 = {0, 0, 0, 0};
    acc1 = __builtin_amdgcn_mfma_f32_16x16x32_bf16(A0, b2, acc1, 0, 0, 0);
    acc1 = __builtin_amdgcn_mfma_f32_16x16x32_bf16(A1, b3, acc1, 0, 0, 0);

#pragma unroll
    for (int r = 0; r < 4; ++r) {
      float c = fmaf(-2.0f, acc0[r], s4[r]);   // key = sq_j - 2*dot
#pragma unroll
      for (int k = 15; k >= 1; --k)
        asm("v_med3_f32 %0, %0, %1, %2" : "+v"(lst0[k]) : "v"(lst0[k - 1]), "v"(c));
      asm("v_min_f32 %0, %0, %1" : "+v"(lst0[0]) : "v"(c));
    }
#pragma unroll
    for (int r = 0; r < 4; ++r) {
      float c = fmaf(-2.0f, acc1[r], s4[r]);
#pragma unroll
      for (int k = 15; k >= 1; --k)
        asm("v_med3_f32 %0, %0, %1, %2" : "+v"(lst1[k]) : "v"(lst1[k - 1]), "v"(c));
      asm("v_min_f32 %0, %0, %1" : "+v"(lst1[0]) : "v"(c));
    }
    A0 = nA0; A1 = nA1; s4 = ns4;
  }

  __shared__ unsigned lists[16 * 547];
  const int sl = wave * 4 + q;
#pragma unroll
  for (int k = 0; k < 16; ++k) {
    lists[sl * 547 + n * 17 + k] = packkey(lst0[k], sl);
    lists[sl * 547 + (n + 16) * 17 + k] = packkey(lst1[k], sl);
  }
  __syncthreads();

  const int sub = lane & 15;
#pragma unroll 1
  for (int pass = 0; pass < 2; ++pass) {
    const int rr = pass * 16 + wave * 4 + (lane >> 4);   // 0..31
    int p = 0;
    unsigned h = lists[sub * 547 + rr * 17];
    float* trow = tops + ((size_t)(ib + rr) * 4 + js) * 16;
#pragma unroll 1
    for (int it = 0; it < 16; ++it) {
      unsigned u = h;
#pragma unroll
      for (int off = 1; off < 16; off <<= 1) {
        unsigned u2 = __shfl_xor(u, off, 64);
        u = (u2 < u) ? u2 : u;
      }
      if (sub == 0)
        __hip_atomic_store(&trow[it], unpackkey(u),
                           __ATOMIC_RELAXED, __HIP_MEMORY_SCOPE_AGENT);
      if ((u & 15u) == (unsigned)sub) { ++p; h = lists[sub * 547 + rr * 17 + p]; }
    }
  }

  // ---- fence-free last-block tail ----
  __syncthreads();                 // drains each wave's vmcnt (trow stores global)
  __shared__ unsigned oldv;
  if (tid == 0)
    oldv = __hip_atomic_fetch_add(&cnt[rg], 1u,
                                  __ATOMIC_RELAXED, __HIP_MEMORY_SCOPE_AGENT);
  __syncthreads();
  if (oldv != 3u) return;

  // stage the 32 rows x 64 sorted candidates into LDS (reuse lists storage)
  float* fbuf = (float*)lists;     // [32][65]
#pragma unroll 1
  for (int j = tid; j < 32 * 64; j += 256) {
    int r = j >> 6, c = j & 63;
    fbuf[r * 65 + c] = __hip_atomic_load(&tops[(size_t)(ib + r) * 64 + c],
                                         __ATOMIC_RELAXED, __HIP_MEMORY_SCOPE_AGENT);
  }
  __syncthreads();
  __shared__ float rsum[32];
  if (tid < 32) {
    const float* bb = fbuf + tid * 65;
    int c0 = 1, c1 = 17, c2 = 33, c3 = 49;
    float h0 = bb[0], h1 = bb[16], h2 = bb[32], h3 = bb[48];
    const float sqr = sq[ib + tid];
    float sum = 0.0f;
#pragma unroll 1
    for (int it = 0; it < 16; ++it) {
      float m = fminf(fminf(h0, h1), fminf(h2, h3));
      sum += sqrtf(fmaxf(sqr + m, 1e-12f));
      if (m == h0)      { h0 = (c0 < 16) ? bb[c0] : 3.0e38f; ++c0; }
      else if (m == h1) { h1 = (c1 < 32) ? bb[c1] : 3.0e38f; ++c1; }
      else if (m == h2) { h2 = (c2 < 48) ? bb[c2] : 3.0e38f; ++c2; }
      else              { h3 = (c3 < 64) ? bb[c3] : 3.0e38f; ++c3; }
    }
    float ir = sum * (1.0f / 16.0f);
    __hip_atomic_store(&intrew[ib + tid], ir,
                       __ATOMIC_RELAXED, __HIP_MEMORY_SCOPE_AGENT);
    rsum[tid] = ir;
  }
  __syncthreads();
  __shared__ unsigned old2s;
  if (tid == 0) {
    float s = 0.0f;
#pragma unroll
    for (int k = 0; k < 32; ++k) s += rsum[k];
    __hip_atomic_fetch_add(psum, s, __ATOMIC_RELAXED, __HIP_MEMORY_SCOPE_AGENT);
    asm volatile("s_waitcnt vmcnt(0)" ::: "memory");  // psum add at coherent point
    old2s = __hip_atomic_fetch_add(cnt2, 1u,
                                   __ATOMIC_RELAXED, __HIP_MEMORY_SCOPE_AGENT);
  }
  __syncthreads();
  if (old2s != 255u) return;

  // global finisher: StreamNorm + reward add
  float total = __hip_atomic_load(psum, __ATOMIC_RELAXED, __HIP_MEMORY_SCOPE_AGENT);
  float mean = total * (1.0f / 8192.0f);
  float mag = 0.99f + 0.01f * mean;
  float inv = 1.0f / (mag + 1e-8f);
#pragma unroll 1
  for (int i = tid; i < NROWS; i += 256) {
    float ir = __hip_atomic_load(&intrew[i], __ATOMIC_RELAXED, __HIP_MEMORY_SCOPE_AGENT);
    int b = i >> 9, ti = i & 511;
    out[i] = reward[b * TT + ti] + ir * inv;
  }
}

extern "C" void kernel_launch(void* const* d_in, const int* in_sizes, int n_in,
                              void* d_out, int out_size, void* d_ws, size_t ws_size,
                              hipStream_t stream) {
  const float* feat   = (const float*)d_in[0];
  const float* reward = (const float*)d_in[1];
  const float* proj   = (const float*)d_in[2];
  float* out = (float*)d_out;

  char* ws = (char*)d_ws;
  unsigned short* sfb = (unsigned short*)ws;                   // 1 MB: sf bf16 [8192][64]
  float* sq           = (float*)(ws + 0x100000);               // 32 KB
  float* intrew       = (float*)(ws + 0x110000);               // 32 KB
  float* psum         = (float*)(ws + 0x120000);               // 4 B
  unsigned* cnt2      = (unsigned*)(ws + 0x120040);            // 4 B
  unsigned* cnt       = (unsigned*)(ws + 0x120100);            // 1 KB
  float* tops         = (float*)(ws + 0x160000);               // 2 MB: [8192][4][16]

  k_sf<<<512, 256, 0, stream>>>(feat, proj, sfb, sq, cnt, psum, cnt2);
  k_knn<<<1024, 256, 0, stream>>>(sfb, sq, tops, intrew, cnt, cnt2, psum, reward, out);
}